// Round 1
// baseline (445.197 us; speedup 1.0000x reference)
//
#include <hip/hip_runtime.h>
#include <hip/hip_bf16.h>

// Problem constants
#define D_DIM   25088
#define B_ROWS  2048
#define C_CLS   100
#define NT      7            // 7 tiles of 16 cols -> 112 padded classes
#define NPAD    112
#define KSTEPS_TOTAL 784     // 25088 / 32
#define SPLITS  16
#define KSTEPS_PER (KSTEPS_TOTAL / SPLITS)  // 49
#define EPS     1e-8f

typedef __bf16 bf16x8 __attribute__((ext_vector_type(8)));
typedef float  f32x4  __attribute__((ext_vector_type(4)));

// RNE float->bf16, pack two into one dword
__device__ __forceinline__ unsigned bfpack2(float lo, float hi) {
    unsigned a = __builtin_bit_cast(unsigned, lo);
    unsigned b = __builtin_bit_cast(unsigned, hi);
    a += 0x7FFFu + ((a >> 16) & 1u);
    b += 0x7FFFu + ((b >> 16) & 1u);
    return (a >> 16) | (b & 0xFFFF0000u);
}

// ---------------- weight norms -> wscale[c] = 1/max(||w_c||, eps) ----------------
__global__ __launch_bounds__(256) void wnorm_kernel(const float* __restrict__ w,
                                                    float* __restrict__ wscale) {
    int c = blockIdx.x;
    const float* row = w + (size_t)c * D_DIM;
    float s = 0.f;
    for (int k = threadIdx.x * 4; k < D_DIM; k += 1024) {
        f32x4 v = *(const f32x4*)(row + k);
        s += v[0]*v[0] + v[1]*v[1] + v[2]*v[2] + v[3]*v[3];
    }
    __shared__ float red[4];
    for (int o = 32; o; o >>= 1) s += __shfl_down(s, o, 64);
    if ((threadIdx.x & 63) == 0) red[threadIdx.x >> 6] = s;
    __syncthreads();
    if (threadIdx.x == 0) {
        float n = sqrtf(red[0] + red[1] + red[2] + red[3]);
        wscale[c] = 1.0f / fmaxf(n, EPS);
    }
}

// ---------------- pack weight into MFMA B-fragment order (bf16) ----------------
// unit u = gstep*7 + t ; lane l holds B[k = gstep*32 + (l>>4)*8 + j][n = t*16 + (l&15)]
// stored at wpack[u*64 + l] as 8 bf16 (uint4).
__global__ __launch_bounds__(256) void wpack_kernel(const float* __restrict__ w,
                                                    uint4* __restrict__ wpack) {
    int unit = blockIdx.x * 4 + (threadIdx.x >> 6);
    int lane = threadIdx.x & 63;
    int t = unit % NT, gstep = unit / NT;
    int col = t * 16 + (lane & 15);
    int k   = gstep * 32 + (lane >> 4) * 8;
    f32x4 a0 = {0.f,0.f,0.f,0.f}, a1 = {0.f,0.f,0.f,0.f};
    if (col < C_CLS) {
        const float* p = w + (size_t)col * D_DIM + k;
        a0 = *(const f32x4*)p;
        a1 = *(const f32x4*)(p + 4);
    }
    uint4 o;
    o.x = bfpack2(a0[0], a0[1]);
    o.y = bfpack2(a0[2], a0[3]);
    o.z = bfpack2(a1[0], a1[1]);
    o.w = bfpack2(a1[2], a1[3]);
    wpack[(size_t)unit * 64 + lane] = o;
}

// ---------------- main GEMM: dot(f_b, w_c) + sumsq(f_b), split-K atomics ----------------
__global__ __launch_bounds__(256) void gemm_kernel(const float* __restrict__ feat,
                                                   const uint4* __restrict__ wpack,
                                                   float* __restrict__ pred,
                                                   float* __restrict__ fnorm2) {
    int tid  = threadIdx.x;
    int wave = tid >> 6, lane = tid & 63;
    int m = lane & 15, quad = lane >> 4;
    int rowbase = blockIdx.x * 64 + wave * 16;
    int row = rowbase + m;
    int gstep0 = blockIdx.y * KSTEPS_PER;

    const float* pA = feat + (size_t)row * D_DIM + gstep0 * 32 + quad * 8;
    const uint4* pB = wpack + (size_t)gstep0 * NT * 64 + lane;

    f32x4 acc[NT];
#pragma unroll
    for (int t = 0; t < NT; ++t) acc[t] = (f32x4){0.f,0.f,0.f,0.f};
    float sumsq = 0.f;

#pragma unroll 2
    for (int s = 0; s < KSTEPS_PER; ++s) {
        f32x4 a0 = *(const f32x4*)(pA);
        f32x4 a1 = *(const f32x4*)(pA + 4);
        sumsq += a0[0]*a0[0] + a0[1]*a0[1] + a0[2]*a0[2] + a0[3]*a0[3]
               + a1[0]*a1[0] + a1[1]*a1[1] + a1[2]*a1[2] + a1[3]*a1[3];
        uint4 ap;
        ap.x = bfpack2(a0[0], a0[1]);
        ap.y = bfpack2(a0[2], a0[3]);
        ap.z = bfpack2(a1[0], a1[1]);
        ap.w = bfpack2(a1[2], a1[3]);
        bf16x8 afrag = __builtin_bit_cast(bf16x8, ap);
#pragma unroll
        for (int t = 0; t < NT; ++t) {
            bf16x8 bfrag = __builtin_bit_cast(bf16x8, pB[t * 64]);
            acc[t] = __builtin_amdgcn_mfma_f32_16x16x32_bf16(afrag, bfrag, acc[t], 0, 0, 0);
        }
        pA += 32;
        pB += NT * 64;
    }

    // sumsq: reduce across the 4 quads that share row m
    sumsq += __shfl_xor(sumsq, 16, 64);
    sumsq += __shfl_xor(sumsq, 32, 64);
    if (quad == 0) atomicAdd(&fnorm2[row], sumsq);

    // C/D layout (16x16x32 bf16): col = lane&15, row = quad*4 + reg
#pragma unroll
    for (int t = 0; t < NT; ++t) {
#pragma unroll
        for (int r = 0; r < 4; ++r) {
            int orow = rowbase + quad * 4 + r;
            int ocol = t * 16 + m;
            atomicAdd(&pred[(size_t)orow * NPAD + ocol], acc[t][r]);
        }
    }
}

// ---------------- per-row log-softmax / NLL / argmax ----------------
__global__ __launch_bounds__(256) void finalize_kernel(const float* __restrict__ pred,
                                                       const float* __restrict__ fnorm2,
                                                       const float* __restrict__ wscale,
                                                       const int* __restrict__ label,
                                                       float* __restrict__ scal) {
    int row = blockIdx.x * 256 + threadIdx.x;
    float nll = 0.f, corr = 0.f, val = 0.f;
    if (row < B_ROWS) {
        float finv = 10.0f / fmaxf(sqrtf(fnorm2[row]), EPS);
        const float* pr = pred + (size_t)row * NPAD;
        float mx = -1e30f; int am = 0;
        for (int c = 0; c < C_CLS; ++c) {
            float lc = pr[c] * wscale[c] * finv;
            if (lc > mx) { mx = lc; am = c; }
        }
        int lab = label[row];
        float se = 0.f, ll = 0.f;
        for (int c = 0; c < C_CLS; ++c) {
            float lc = pr[c] * wscale[c] * finv;
            se += expf(lc - mx);
            if (c == lab) ll = lc;
        }
        if (lab >= 0) {
            float lse = mx + logf(se);
            nll  = lse - ll;
            val  = 1.f;
            corr = (am == lab) ? 1.f : 0.f;
        }
    }
    for (int o = 32; o; o >>= 1) {
        nll  += __shfl_down(nll, o, 64);
        corr += __shfl_down(corr, o, 64);
        val  += __shfl_down(val, o, 64);
    }
    if ((threadIdx.x & 63) == 0) {
        atomicAdd(&scal[0], nll);
        atomicAdd(&scal[1], corr);
        atomicAdd(&scal[2], val);
    }
}

__global__ void out_kernel(const float* __restrict__ scal, float* __restrict__ out) {
    out[0] = scal[0] / fmaxf(scal[2], 1.0f);
    out[1] = scal[1] / (scal[2] + 1e-10f);
}

// Workspace layout (bytes):
//   [0, 917504)          pred partials   2048*112 f32   (zeroed)
//   [917504, 925696)     fnorm2          2048 f32       (zeroed)
//   [925696, 925712)     scalars         4 f32          (zeroed, 3 used)
//   [925712, 926160)     wscale          112 f32
//   [926720, 6546432)    wpack bf16 B-fragments (784*7*64 uint4)
extern "C" void kernel_launch(void* const* d_in, const int* in_sizes, int n_in,
                              void* d_out, int out_size, void* d_ws, size_t ws_size,
                              hipStream_t stream) {
    const float* feat   = (const float*)d_in[0];
    const int*   label  = (const int*)d_in[1];
    const float* weight = (const float*)d_in[2];
    float* out = (float*)d_out;

    char* ws = (char*)d_ws;
    float* pred   = (float*)(ws);
    float* fnorm2 = (float*)(ws + 917504);
    float* scal   = (float*)(ws + 925696);
    float* wscale = (float*)(ws + 925712);
    uint4* wpack  = (uint4*)(ws + 926720);

    hipMemsetAsync(ws, 0, 925712, stream);
    wnorm_kernel<<<C_CLS, 256, 0, stream>>>(weight, wscale);
    wpack_kernel<<<KSTEPS_TOTAL * NT / 4, 256, 0, stream>>>(weight, wpack);
    gemm_kernel<<<dim3(B_ROWS / 64, SPLITS), 256, 0, stream>>>(feat, wpack, pred, fnorm2);
    finalize_kernel<<<B_ROWS / 256, 256, 0, stream>>>(pred, fnorm2, wscale, label, scal);
    out_kernel<<<1, 1, 0, stream>>>(scal, out);
}

// Round 2
// 364.661 us; speedup vs baseline: 1.2209x; 1.2209x over previous
//
#include <hip/hip_runtime.h>
#include <hip/hip_bf16.h>

// Problem constants
#define D_DIM   25088
#define B_ROWS  2048
#define C_CLS   100
#define NT      7            // 7 tiles of 16 cols -> 112 padded classes
#define NPAD    112
#define KSTEPS_TOTAL 784     // 25088 / 32
#define SPLITS  56
#define KSTEPS_PER (KSTEPS_TOTAL / SPLITS)  // 14
#define EPS     1e-8f

typedef __bf16 bf16x8 __attribute__((ext_vector_type(8)));
typedef float  f32x4  __attribute__((ext_vector_type(4)));
typedef float  f32x2  __attribute__((ext_vector_type(2)));

// RNE float->bf16, pack two into one dword
__device__ __forceinline__ unsigned bfpack2(float lo, float hi) {
    unsigned a = __builtin_bit_cast(unsigned, lo);
    unsigned b = __builtin_bit_cast(unsigned, hi);
    a += 0x7FFFu + ((a >> 16) & 1u);
    b += 0x7FFFu + ((b >> 16) & 1u);
    return (a >> 16) | (b & 0xFFFF0000u);
}

// ---------------- prep: per-class norm + pack weight into MFMA B-fragment order ----
// One block per (padded) class row c. Reads weight row coalesced exactly once.
// wpack layout: unit u = gstep*7 + t; lane l = quad*16 + n holds
//   B[k = gstep*32 + quad*8 + j][col = t*16 + n], j=0..7, as 8 bf16 (uint4).
__global__ __launch_bounds__(256) void prep_kernel(const float* __restrict__ w,
                                                   float* __restrict__ wscale,
                                                   unsigned* __restrict__ wpack) {
    int c = blockIdx.x;              // 0..111
    int t = c >> 4, n = c & 15;
    bool real = (c < C_CLS);
    const float* row = w + (size_t)c * D_DIM;
    float s = 0.f;
    for (int i = 0; i < 49; ++i) {
        int d = i * 512 + threadIdx.x * 2;
        f32x2 v = {0.f, 0.f};
        if (real) v = *(const f32x2*)(row + d);
        s += v[0]*v[0] + v[1]*v[1];
        int gstep = d >> 5, r = d & 31, quad = r >> 3, j = r & 7;
        unsigned dw = bfpack2(v[0], v[1]);
        size_t idx = ((size_t)(gstep * 7 + t) * 64 + quad * 16 + n) * 4 + (j >> 1);
        wpack[idx] = dw;
    }
    if (!real) return;
    __shared__ float red[4];
    for (int o = 32; o; o >>= 1) s += __shfl_down(s, o, 64);
    if ((threadIdx.x & 63) == 0) red[threadIdx.x >> 6] = s;
    __syncthreads();
    if (threadIdx.x == 0) {
        float nn = sqrtf(red[0] + red[1] + red[2] + red[3]);
        wscale[c] = 1.0f / fmaxf(nn, EPS);
    }
}

// ---------------- main GEMM: dot(f_b, w_c) + sumsq(f_b), split-K atomics ----------------
__global__ __launch_bounds__(256, 4) void gemm_kernel(const float* __restrict__ feat,
                                                      const uint4* __restrict__ wpack,
                                                      float* __restrict__ pred,
                                                      float* __restrict__ fnorm2) {
    int tid  = threadIdx.x;
    int wave = tid >> 6, lane = tid & 63;
    int m = lane & 15, quad = lane >> 4;
    int rowbase = blockIdx.x * 64 + wave * 16;
    int row = rowbase + m;
    int gstep0 = blockIdx.y * KSTEPS_PER;

    const float* pA = feat + (size_t)row * D_DIM + gstep0 * 32 + quad * 8;
    const uint4* pB = wpack + (size_t)gstep0 * NT * 64 + lane;

    f32x4 acc[NT];
#pragma unroll
    for (int t = 0; t < NT; ++t) acc[t] = (f32x4){0.f,0.f,0.f,0.f};
    float sumsq = 0.f;

    f32x4 a0 = *(const f32x4*)(pA);
    f32x4 a1 = *(const f32x4*)(pA + 4);

    for (int s = 0; s < KSTEPS_PER; ++s) {
        // prefetch next step's A (clamped on last iter to avoid OOB)
        const float* pn = pA + ((s + 1 < KSTEPS_PER) ? 32 : 0);
        f32x4 n0 = *(const f32x4*)(pn);
        f32x4 n1 = *(const f32x4*)(pn + 4);

        sumsq += a0[0]*a0[0] + a0[1]*a0[1] + a0[2]*a0[2] + a0[3]*a0[3]
               + a1[0]*a1[0] + a1[1]*a1[1] + a1[2]*a1[2] + a1[3]*a1[3];
        uint4 ap;
        ap.x = bfpack2(a0[0], a0[1]);
        ap.y = bfpack2(a0[2], a0[3]);
        ap.z = bfpack2(a1[0], a1[1]);
        ap.w = bfpack2(a1[2], a1[3]);
        bf16x8 afrag = __builtin_bit_cast(bf16x8, ap);
#pragma unroll
        for (int t = 0; t < NT; ++t) {
            bf16x8 bfrag = __builtin_bit_cast(bf16x8, pB[t * 64]);
            acc[t] = __builtin_amdgcn_mfma_f32_16x16x32_bf16(afrag, bfrag, acc[t], 0, 0, 0);
        }
        a0 = n0; a1 = n1;
        pA += 32;
        pB += NT * 64;
    }

    // sumsq: reduce across the 4 quads that share row m
    sumsq += __shfl_xor(sumsq, 16, 64);
    sumsq += __shfl_xor(sumsq, 32, 64);
    if (quad == 0) atomicAdd(&fnorm2[row], sumsq);

    // C/D layout (16x16x32 bf16): col = lane&15, row = quad*4 + reg
#pragma unroll
    for (int t = 0; t < NT; ++t) {
#pragma unroll
        for (int r = 0; r < 4; ++r) {
            int orow = rowbase + quad * 4 + r;
            int ocol = t * 16 + m;
            atomicAdd(&pred[(size_t)orow * NPAD + ocol], acc[t][r]);
        }
    }
}

// ---------------- per-row log-softmax / NLL / argmax: one wave per row ----------------
__global__ __launch_bounds__(256) void finalize_kernel(const float* __restrict__ pred,
                                                       const float* __restrict__ fnorm2,
                                                       const float* __restrict__ wscale,
                                                       const int* __restrict__ label,
                                                       float* __restrict__ scal) {
    int gwave = (blockIdx.x * 256 + threadIdx.x) >> 6;
    int lane = threadIdx.x & 63;
    int row = gwave;
    if (row >= B_ROWS) return;
    float finv = 10.0f / fmaxf(sqrtf(fnorm2[row]), EPS);
    const float* pr = pred + (size_t)row * NPAD;

    int c0 = lane, c1 = lane + 64;
    float l0 = (c0 < C_CLS) ? pr[c0] * wscale[c0] * finv : -1e30f;
    float l1 = (c1 < C_CLS) ? pr[c1] * wscale[c1] * finv : -1e30f;

    // argmax (first-max tie rule: keep smaller index on ties)
    float mx = l0; int am = c0;
    if (l1 > mx) { mx = l1; am = c1; }
    for (int o = 1; o < 64; o <<= 1) {
        float om = __shfl_xor(mx, o, 64);
        int   oa = __shfl_xor(am, o, 64);
        if (om > mx || (om == mx && oa < am)) { mx = om; am = oa; }
    }
    float se = expf(l0 - mx) + expf(l1 - mx);
    for (int o = 1; o < 64; o <<= 1) se += __shfl_xor(se, o, 64);

    int lab = label[row];
    int labc = (lab < 0) ? 0 : lab;
    float lv = (labc >= 64) ? l1 : l0;
    float ll = __shfl(lv, labc & 63, 64);

    if (lane == 0 && lab >= 0) {
        float lse = mx + logf(se);
        atomicAdd(&scal[0], lse - ll);
        atomicAdd(&scal[1], (am == lab) ? 1.f : 0.f);
        atomicAdd(&scal[2], 1.f);
    }
}

__global__ void out_kernel(const float* __restrict__ scal, float* __restrict__ out) {
    out[0] = scal[0] / fmaxf(scal[2], 1.0f);
    out[1] = scal[1] / (scal[2] + 1e-10f);
}

// Workspace layout (bytes):
//   [0, 917504)          pred partials   2048*112 f32   (zeroed)
//   [917504, 925696)     fnorm2          2048 f32       (zeroed)
//   [925696, 925712)     scalars         4 f32          (zeroed, 3 used)
//   [925712, 926160)     wscale          112 f32
//   [926720, 6546432)    wpack bf16 B-fragments (784*7*64 uint4)
extern "C" void kernel_launch(void* const* d_in, const int* in_sizes, int n_in,
                              void* d_out, int out_size, void* d_ws, size_t ws_size,
                              hipStream_t stream) {
    const float* feat   = (const float*)d_in[0];
    const int*   label  = (const int*)d_in[1];
    const float* weight = (const float*)d_in[2];
    float* out = (float*)d_out;

    char* ws = (char*)d_ws;
    float* pred   = (float*)(ws);
    float* fnorm2 = (float*)(ws + 917504);
    float* scal   = (float*)(ws + 925696);
    float* wscale = (float*)(ws + 925712);
    uint4* wpack  = (uint4*)(ws + 926720);

    hipMemsetAsync(ws, 0, 925712, stream);
    prep_kernel<<<NPAD, 256, 0, stream>>>(weight, wscale, (unsigned*)wpack);
    gemm_kernel<<<dim3(B_ROWS / 64, SPLITS), 256, 0, stream>>>(feat, wpack, pred, fnorm2);
    finalize_kernel<<<B_ROWS / 4 / 64, 256, 0, stream>>>(pred, fnorm2, wscale, label, scal);
    out_kernel<<<1, 1, 0, stream>>>(scal, out);
}